// Round 8
// baseline (314.364 us; speedup 1.0000x reference)
//
#include <hip/hip_runtime.h>
#include <math.h>

#define BN_EPS 1e-5f

typedef unsigned short u16;
typedef unsigned int u32;
typedef __attribute__((ext_vector_type(8))) short bf16x8;
typedef __attribute__((ext_vector_type(4))) float f32x4;

__device__ __forceinline__ float bf2f(u16 b) {
  return __uint_as_float(((u32)b) << 16);
}
__device__ __forceinline__ u16 f2bf(float f) {
  u32 u = __float_as_uint(f);
  u32 r = (u + 0x7fffu + ((u >> 16) & 1u)) >> 16;   // RNE
  return (u16)r;
}
__device__ __forceinline__ u32 packbf2(float x, float y) {
  return (u32)f2bf(x) | ((u32)f2bf(y) << 16);
}
__device__ __forceinline__ float lo_bf(u32 p) { return __uint_as_float(p << 16); }
__device__ __forceinline__ float hi_bf(u32 p) { return __uint_as_float(p & 0xffff0000u); }

__device__ __forceinline__ void unpack8(uint4 p, float* f) {
  f[0] = lo_bf(p.x); f[1] = hi_bf(p.x);
  f[2] = lo_bf(p.y); f[3] = hi_bf(p.y);
  f[4] = lo_bf(p.z); f[5] = hi_bf(p.z);
  f[6] = lo_bf(p.w); f[7] = hi_bf(p.w);
}
__device__ __forceinline__ void unpack4(uint2 p, float* f) {
  f[0] = lo_bf(p.x); f[1] = hi_bf(p.x);
  f[2] = lo_bf(p.y); f[3] = hi_bf(p.y);
}

// ---------------- CSR build ----------------
__global__ __launch_bounds__(256) void count_pos_k(const int* __restrict__ dst,
                                                   int* __restrict__ cnt,
                                                   int* __restrict__ pintra,
                                                   int T, int E) {
  int t = blockIdx.x * 256 + threadIdx.x;
  if (t >= T) return;
  int e0 = t, e1 = t + T, e2 = t + 2 * T, e3 = t + 3 * T;
  int d0 = (e0 < E) ? dst[e0] : -1;
  int d1 = (e1 < E) ? dst[e1] : -1;
  int d2 = (e2 < E) ? dst[e2] : -1;
  int d3 = (e3 < E) ? dst[e3] : -1;
  int p0 = (d0 >= 0) ? atomicAdd(&cnt[d0], 1) : 0;
  int p1 = (d1 >= 0) ? atomicAdd(&cnt[d1], 1) : 0;
  int p2 = (d2 >= 0) ? atomicAdd(&cnt[d2], 1) : 0;
  int p3 = (d3 >= 0) ? atomicAdd(&cnt[d3], 1) : 0;
  if (d0 >= 0) pintra[e0] = p0;
  if (d1 >= 0) pintra[e1] = p1;
  if (d2 >= 0) pintra[e2] = p2;
  if (d3 >= 0) pintra[e3] = p3;
}

__global__ __launch_bounds__(256) void blocksum_k(const int* __restrict__ cnt,
                                                  int* __restrict__ bsum, int n) {
  __shared__ int red[256];
  int tid = threadIdx.x;
  int i = blockIdx.x * 256 + tid;
  int v = (i < n) ? cnt[i] : 0;
  red[tid] = v;
  __syncthreads();
  for (int o = 128; o > 0; o >>= 1) {
    if (tid < o) red[tid] += red[tid + o];
    __syncthreads();
  }
  if (tid == 0) bsum[blockIdx.x] = red[0];
}

__global__ __launch_bounds__(1024) void scan_bsum_k(int* __restrict__ bsum, int nb) {
  __shared__ int part[1024];
  int tid = threadIdx.x;
  int v = (tid < nb) ? bsum[tid] : 0;
  part[tid] = v;
  __syncthreads();
  for (int o = 1; o < 1024; o <<= 1) {
    int t = (tid >= o) ? part[tid - o] : 0;
    __syncthreads();
    part[tid] += t;
    __syncthreads();
  }
  if (tid < nb) bsum[tid] = part[tid] - v;   // exclusive
}

__global__ __launch_bounds__(256) void scan_final_k(const int* __restrict__ cnt,
                                                    const int* __restrict__ bsum,
                                                    int* __restrict__ rowptr,
                                                    float* __restrict__ dinv, int n) {
  __shared__ int part[256];
  int tid = threadIdx.x;
  int i = blockIdx.x * 256 + tid;
  int v = (i < n) ? cnt[i] : 0;
  part[tid] = v;
  __syncthreads();
  for (int o = 1; o < 256; o <<= 1) {
    int t = (tid >= o) ? part[tid - o] : 0;
    __syncthreads();
    part[tid] += t;
    __syncthreads();
  }
  if (i < n) {
    int excl = part[tid] - v + bsum[blockIdx.x];
    rowptr[i] = excl;
    dinv[i] = rsqrtf((float)(v + 1));   // deg = in-degree + self-loop
    if (i == n - 1) rowptr[n] = excl + v;
  }
}

__global__ __launch_bounds__(256) void fill_csr_k(const int* __restrict__ src,
                                                  const int* __restrict__ dst,
                                                  const int* __restrict__ rowptr,
                                                  const int* __restrict__ pintra,
                                                  int2* __restrict__ se, int T, int E) {
  int t = blockIdx.x * 256 + threadIdx.x;
  if (t >= T) return;
  #pragma unroll
  for (int u = 0; u < 4; ++u) {
    int e = t + u * T;
    if (e < E) {
      int d = dst[e];
      int p = rowptr[d] + pintra[e];
      se[p] = make_int2(src[e], e);
    }
  }
}

// ---- weight prep: 4 matrices [K=128][N=128] fp32 -> transposed bf16 Wt[n][k] ----
__global__ __launch_bounds__(256) void wconv_k(const float* __restrict__ W1,
    const float* __restrict__ W2, const float* __restrict__ epW1,
    u16* __restrict__ out) {
  int t = blockIdx.x * 256 + threadIdx.x;   // 4 * 16384
  int m = t >> 14, r = t & 16383;
  int n = r >> 7, k = r & 127;
  const float* src = (m == 0) ? W1 : (m == 1) ? W2 : epW1 + (size_t)(m - 2) * 16384;
  out[t] = f2bf(src[k * 128 + n]);
}

// ---- MFMA GEMM: Y_bf16[M,128] = (X[M,128] @ W) (+bias) (* dinv[row]) ----
template<bool BF16IN, bool SCALE, bool BIAS>
__global__ __launch_bounds__(256) void gemm_mfma_k(const void* __restrict__ Xv,
    const u16* __restrict__ Wt, const float* __restrict__ bias,
    const float* __restrict__ dinv, u16* __restrict__ Y, int M) {
  __shared__ u16 Xs[64][136];
  __shared__ u16 Ws[128][136];
  int tid = threadIdx.x;
  int row0 = blockIdx.x * 64;
  for (int i = tid; i < 2048; i += 256) {
    int n = i >> 4, c8 = i & 15;
    uint4 v = ((const uint4*)Wt)[i];
    *(uint4*)&Ws[n][c8 * 8] = v;
  }
  for (int i = tid; i < 1024; i += 256) {
    int r = i >> 4, c8 = i & 15;
    int gr = row0 + r;
    uint4 v = make_uint4(0u, 0u, 0u, 0u);
    if (gr < M) {
      if (BF16IN) {
        v = ((const uint4*)Xv)[(size_t)gr * 16 + c8];
      } else {
        float4 f0 = ((const float4*)Xv)[(size_t)gr * 32 + c8 * 2];
        float4 f1 = ((const float4*)Xv)[(size_t)gr * 32 + c8 * 2 + 1];
        v.x = packbf2(f0.x, f0.y); v.y = packbf2(f0.z, f0.w);
        v.z = packbf2(f1.x, f1.y); v.w = packbf2(f1.z, f1.w);
      }
    }
    *(uint4*)&Xs[r][c8 * 8] = v;
  }
  __syncthreads();
  int w = tid >> 6, l = tid & 63;
  int lr = l & 15, kq = l >> 4;
  bf16x8 a[4];
  #pragma unroll
  for (int kk = 0; kk < 4; ++kk)
    a[kk] = *(const bf16x8*)&Xs[w * 16 + lr][kk * 32 + kq * 8];
  f32x4 acc[8];
  #pragma unroll
  for (int ct = 0; ct < 8; ++ct) {
    f32x4 c = {0.f, 0.f, 0.f, 0.f};
    #pragma unroll
    for (int kk = 0; kk < 4; ++kk) {
      bf16x8 b = *(const bf16x8*)&Ws[ct * 16 + lr][kk * 32 + kq * 8];
      c = __builtin_amdgcn_mfma_f32_16x16x32_bf16(a[kk], b, c, 0, 0, 0);
    }
    acc[ct] = c;
  }
  float sc[4];
  #pragma unroll
  for (int r = 0; r < 4; ++r) {
    int grow = row0 + w * 16 + kq * 4 + r;
    sc[r] = (SCALE && grow < M) ? dinv[grow] : 1.f;
  }
  #pragma unroll
  for (int ct = 0; ct < 8; ++ct) {
    int n = ct * 16 + lr;
    float bv = BIAS ? bias[n] : 0.f;
    #pragma unroll
    for (int r = 0; r < 4; ++r) {
      int grow = row0 + w * 16 + kq * 4 + r;
      if (grow < M) {
        float o = acc[ct][r] + bv;
        if (SCALE) o *= sc[r];
        Y[(size_t)grow * 128 + n] = f2bf(o);
      }
    }
  }
}

// ---- fused double GEMM: YA = X@WA + bias, YB = X@WB; outputs in BLOCKED layout ----
// blocked: Y[(n>>5)*M*32 + row*32 + (n&31)]  (4 channel-slices of 32, each [M][32])
__global__ __launch_bounds__(256) void gemm_mfma2_k(const u16* __restrict__ X,
    const u16* __restrict__ WtA, const u16* __restrict__ WtB,
    const float* __restrict__ bias, u16* __restrict__ YA, u16* __restrict__ YB, int M) {
  __shared__ u16 Xs[64][136];
  __shared__ u16 Ws[128][136];
  int tid = threadIdx.x;
  int row0 = blockIdx.x * 64;
  for (int i = tid; i < 1024; i += 256) {
    int r = i >> 4, c8 = i & 15;
    int gr = row0 + r;
    uint4 v = make_uint4(0u, 0u, 0u, 0u);
    if (gr < M) v = ((const uint4*)X)[(size_t)gr * 16 + c8];
    *(uint4*)&Xs[r][c8 * 8] = v;
  }
  __syncthreads();
  int w = tid >> 6, l = tid & 63;
  int lr = l & 15, kq = l >> 4;
  bf16x8 a[4];
  #pragma unroll
  for (int kk = 0; kk < 4; ++kk)
    a[kk] = *(const bf16x8*)&Xs[w * 16 + lr][kk * 32 + kq * 8];

  for (int m = 0; m < 2; ++m) {
    const u16* Wt = m ? WtB : WtA;
    u16* Y = m ? YB : YA;
    __syncthreads();
    for (int i = tid; i < 2048; i += 256) {
      int n = i >> 4, c8 = i & 15;
      uint4 v = ((const uint4*)Wt)[i];
      *(uint4*)&Ws[n][c8 * 8] = v;
    }
    __syncthreads();
    #pragma unroll
    for (int ct = 0; ct < 8; ++ct) {
      f32x4 c = {0.f, 0.f, 0.f, 0.f};
      #pragma unroll
      for (int kk = 0; kk < 4; ++kk) {
        bf16x8 b = *(const bf16x8*)&Ws[ct * 16 + lr][kk * 32 + kq * 8];
        c = __builtin_amdgcn_mfma_f32_16x16x32_bf16(a[kk], b, c, 0, 0, 0);
      }
      int n = ct * 16 + lr;
      float bv = (m == 0) ? bias[n] : 0.f;
      size_t sbase = (size_t)(n >> 5) * M * 32 + (n & 31);
      #pragma unroll
      for (int r = 0; r < 4; ++r) {
        int grow = row0 + w * 16 + kq * 4 + r;
        if (grow < M) Y[sbase + (size_t)grow * 32] = f2bf(c[r] + bv);
      }
    }
  }
}

// --- agg: wave per node, 4 edges/iteration (row-major XW, unchanged) ---
__global__ __launch_bounds__(256) void agg_bn_relu_k(const uint4* __restrict__ XW4,
    const int* __restrict__ rowptr, const int2* __restrict__ se,
    const float* __restrict__ dinv,
    const float* __restrict__ bb, const float* __restrict__ g,
    const float* __restrict__ be, const float* __restrict__ mm,
    const float* __restrict__ vv,
    uint4* __restrict__ H4, int n) {
  int node = (blockIdx.x * 256 + threadIdx.x) >> 6;
  if (node >= n) return;
  int lane = threadIdx.x & 63;
  int sub = lane >> 4, l16 = lane & 15;
  int beg = rowptr[node], end = rowptr[node + 1];
  float ac[8];
  #pragma unroll
  for (int j = 0; j < 8; ++j) ac[j] = 0.f;
  for (int i = beg; i < end; i += 4) {
    int idx = i + sub;
    if (idx < end) {
      int s = se[idx].x;
      uint4 p = XW4[(size_t)s * 16 + l16];
      float f[8];
      unpack8(p, f);
      #pragma unroll
      for (int j = 0; j < 8; ++j) ac[j] += f[j];
    }
  }
  #pragma unroll
  for (int j = 0; j < 8; ++j) {
    ac[j] += __shfl_xor(ac[j], 16);
    ac[j] += __shfl_xor(ac[j], 32);
  }
  {
    uint4 p = XW4[(size_t)node * 16 + l16];
    float f[8];
    unpack8(p, f);
    #pragma unroll
    for (int j = 0; j < 8; ++j) ac[j] += f[j];
  }
  float dn = dinv[node];
  int c = l16 * 8;
  float4 g0 = *(const float4*)&g[c],  g1 = *(const float4*)&g[c + 4];
  float4 v0 = *(const float4*)&vv[c], v1 = *(const float4*)&vv[c + 4];
  float4 b0 = *(const float4*)&bb[c], b1 = *(const float4*)&bb[c + 4];
  float4 m0 = *(const float4*)&mm[c], m1 = *(const float4*)&mm[c + 4];
  float4 e0 = *(const float4*)&be[c], e1 = *(const float4*)&be[c + 4];
  float gg[8] = {g0.x, g0.y, g0.z, g0.w, g1.x, g1.y, g1.z, g1.w};
  float vvv[8] = {v0.x, v0.y, v0.z, v0.w, v1.x, v1.y, v1.z, v1.w};
  float bbb[8] = {b0.x, b0.y, b0.z, b0.w, b1.x, b1.y, b1.z, b1.w};
  float mmm[8] = {m0.x, m0.y, m0.z, m0.w, m1.x, m1.y, m1.z, m1.w};
  float eee[8] = {e0.x, e0.y, e0.z, e0.w, e1.x, e1.y, e1.z, e1.w};
  u32 out[4];
  #pragma unroll
  for (int j2 = 0; j2 < 4; ++j2) {
    float o0 = (ac[2*j2]   * dn + bbb[2*j2]   - mmm[2*j2])   * (gg[2*j2]   * rsqrtf(vvv[2*j2]   + BN_EPS)) + eee[2*j2];
    float o1 = (ac[2*j2+1] * dn + bbb[2*j2+1] - mmm[2*j2+1]) * (gg[2*j2+1] * rsqrtf(vvv[2*j2+1] + BN_EPS)) + eee[2*j2+1];
    out[j2] = packbf2(fmaxf(o0, 0.f), fmaxf(o1, 0.f));
  }
  if (sub == 0) {
    uint4 pk = make_uint4(out[0], out[1], out[2], out[3]);
    H4[(size_t)node * 16 + l16] = pk;
  }
}

// --- edge MLP pass: channel-slice pass (blockIdx.y = pass 0..3) ---
// A,B in blocked layout [4][N][32]; wave per node: 8 subs x 8 lanes, lane = 4 chans.
// writes part[pass*E + csr_pos] = partial dot (no atomics).
__global__ __launch_bounds__(256) void edge_pass_k(const u16* __restrict__ Ab,
    const u16* __restrict__ Bb, const int* __restrict__ rowptr,
    const int2* __restrict__ se, const float* __restrict__ w2,
    float* __restrict__ part, int n, int E) {
  int node = (blockIdx.x * 256 + threadIdx.x) >> 6;
  if (node >= n) return;
  int pass = blockIdx.y;
  int lane = threadIdx.x & 63;
  int sub = lane >> 3, l8 = lane & 7;
  int beg = rowptr[node], end = rowptr[node + 1];
  if (beg >= end) return;
  const uint2* A2 = (const uint2*)(Ab + (size_t)pass * n * 32);
  const uint2* B2 = (const uint2*)(Bb + (size_t)pass * n * 32);
  float bv[4];
  unpack4(B2[(size_t)node * 8 + l8], bv);
  int c = pass * 32 + l8 * 4;
  float4 wv4 = *(const float4*)&w2[c];
  float wv[4] = {wv4.x, wv4.y, wv4.z, wv4.w};
  float* pout = part + (size_t)pass * E;
  for (int i = beg; i < end; i += 8) {
    int idx = i + sub;
    if (idx < end) {
      int s = se[idx].x;
      float f[4];
      unpack4(A2[(size_t)s * 8 + l8], f);
      float dot;
      dot = fmaxf(f[0] + bv[0], 0.f) * wv[0];
      dot = fmaf(fmaxf(f[1] + bv[1], 0.f), wv[1], dot);
      dot = fmaf(fmaxf(f[2] + bv[2], 0.f), wv[2], dot);
      dot = fmaf(fmaxf(f[3] + bv[3], 0.f), wv[3], dot);
      dot += __shfl_xor(dot, 1);
      dot += __shfl_xor(dot, 2);
      dot += __shfl_xor(dot, 4);
      if (l8 == 0) pout[idx] = dot;
    }
  }
}

// --- finalize: out[eid] = sigmoid(sum of 4 partials + b2) ---
__global__ __launch_bounds__(256) void edge_fin_k(const float* __restrict__ part,
    const int2* __restrict__ se, const float* __restrict__ b2,
    float* __restrict__ out, int E) {
  int t = blockIdx.x * 256 + threadIdx.x;
  if (t >= E) return;
  float z = part[t] + part[(size_t)E + t] + part[2 * (size_t)E + t] +
            part[3 * (size_t)E + t] + b2[0];
  out[se[t].y] = 1.f / (1.f + expf(-z));
}

extern "C" void kernel_launch(void* const* d_in, const int* in_sizes, int n_in,
                              void* d_out, int out_size, void* d_ws, size_t ws_size,
                              hipStream_t stream) {
  const float* x    = (const float*)d_in[0];
  const int*   ei   = (const int*)d_in[1];
  const float* W1   = (const float*)d_in[2];
  const float* b1   = (const float*)d_in[3];
  const float* g1   = (const float*)d_in[4];
  const float* be1  = (const float*)d_in[5];
  const float* m1   = (const float*)d_in[6];
  const float* v1   = (const float*)d_in[7];
  const float* W2   = (const float*)d_in[8];
  const float* b2   = (const float*)d_in[9];
  const float* g2   = (const float*)d_in[10];
  const float* be2  = (const float*)d_in[11];
  const float* m2   = (const float*)d_in[12];
  const float* v2   = (const float*)d_in[13];
  const float* epW1 = (const float*)d_in[14];
  const float* epb1 = (const float*)d_in[15];
  const float* epW2 = (const float*)d_in[16];
  const float* epb2 = (const float*)d_in[17];

  int N = in_sizes[0] / 128;
  int E = in_sizes[1] / 2;
  const int* src = ei;
  const int* dst = ei + E;

  char* w = (char*)d_ws;
  size_t off = 0;
  auto carve = [&](size_t bytes) {
    void* p = w + off;
    off = (off + bytes + 255) & ~(size_t)255;
    return p;
  };
  u16* bufX  = (u16*)carve((size_t)N * 128 * 2);  // xw' -> t2' -> A(blocked)
  u16* bufH  = (u16*)carve((size_t)N * 128 * 2);  // h1 -> h2
  u16* bufB  = (u16*)carve((size_t)N * 128 * 2);  // B(blocked)
  int*   cnt   = (int*)carve((size_t)N * 4);
  int*   pintra= (int*)carve((size_t)E * 4);
  int*   rowptr= (int*)carve((size_t)(N + 1) * 4);
  float* dinv  = (float*)carve((size_t)N * 4);
  int2*  se    = (int2*)carve((size_t)E * 8);
  int*   bsum  = (int*)carve((size_t)1024 * 4);
  u16*   wsT   = (u16*)carve((size_t)4 * 16384 * 2);
  float* part  = (float*)carve((size_t)4 * E * 4);   // edge partial dots
  (void)ws_size; (void)n_in; (void)out_size;

  int nb = (N + 255) / 256;
  int T = (E + 3) / 4;
  int tb = (T + 255) / 256;

  hipMemsetAsync(cnt, 0, (size_t)N * 4, stream);
  wconv_k<<<256, 256, 0, stream>>>(W1, W2, epW1, wsT);
  count_pos_k<<<tb, 256, 0, stream>>>(dst, cnt, pintra, T, E);
  blocksum_k<<<nb, 256, 0, stream>>>(cnt, bsum, N);
  scan_bsum_k<<<1, 1024, 0, stream>>>(bsum, nb);
  scan_final_k<<<nb, 256, 0, stream>>>(cnt, bsum, rowptr, dinv, N);
  fill_csr_k<<<tb, 256, 0, stream>>>(src, dst, rowptr, pintra, se, T, E);

  int gb = (N + 63) / 64;
  int ab = (N + 3) / 4;   // wave-per-node kernels
  const u16* WtW1 = wsT;
  const u16* WtW2 = wsT + 16384;
  const u16* WtA  = wsT + 2 * 16384;
  const u16* WtB  = wsT + 3 * 16384;

  // layer 1: XW' = dinv * (x @ W1)
  gemm_mfma_k<false, true, false><<<gb, 256, 0, stream>>>(x, WtW1, nullptr, dinv, bufX, N);
  agg_bn_relu_k<<<ab, 256, 0, stream>>>((const uint4*)bufX, rowptr, se, dinv,
                                        b1, g1, be1, m1, v1, (uint4*)bufH, N);
  // layer 2
  gemm_mfma_k<true, true, false><<<gb, 256, 0, stream>>>(bufH, WtW2, nullptr, dinv, bufX, N);
  agg_bn_relu_k<<<ab, 256, 0, stream>>>((const uint4*)bufX, rowptr, se, dinv,
                                        b2, g2, be2, m2, v2, (uint4*)bufH, N);
  // edge predictor GEMMs (fused), outputs in blocked [4][N][32] layout
  gemm_mfma2_k<<<gb, 256, 0, stream>>>(bufH, WtA, WtB, epb1, bufX, bufB, N);
  // edge MLP: 4 channel-slice passes (L2-resident 3.2MB slices) + finalize
  edge_pass_k<<<dim3(ab, 4), 256, 0, stream>>>(bufX, bufB, rowptr, se, epW2,
                                               part, N, E);
  edge_fin_k<<<(E + 255) / 256, 256, 0, stream>>>(part, se, epb2, (float*)d_out, E);
}